// Round 13
// baseline (230.781 us; speedup 1.0000x reference)
//
#include <hip/hip_runtime.h>
#include <hip/hip_fp16.h>
#include <math.h>

#define NTAB 9801
typedef unsigned int uint;
typedef float f2v __attribute__((ext_vector_type(2)));
typedef _Float16 h2v __attribute__((ext_vector_type(2)));

struct WParams { float w1[7]; float wd[3]; };

// ---------- packed-half helpers ----------
__device__ inline __half2 u2h2(uint u) { return __builtin_bit_cast(__half2, u); }
__device__ inline float flo(uint u) { return __low2float(u2h2(u)); }
__device__ inline float fhi(uint u) { return __high2float(u2h2(u)); }
__device__ inline uint pkmul(uint a, uint b) { return __builtin_bit_cast(uint, __hmul2(u2h2(a), u2h2(b))); }
__device__ inline uint pack2(float a, float b) {   // v_cvt_pkrtz_f16_f32
    return __builtin_bit_cast(uint, __builtin_amdgcn_cvt_pkrtz(a, b));
}
__device__ inline uint algn16(uint hi, uint lo) {   // (hi:lo)>>16 -> v_alignbit
    return (uint)((((unsigned long long)hi << 32) | lo) >> 16);
}
__device__ inline float fdot2f(uint a, uint b, float c) {
    return __builtin_amdgcn_fdot2(__builtin_bit_cast(h2v, a), __builtin_bit_cast(h2v, b), c, false);
}
__device__ inline float rcpf(float x) { return __builtin_amdgcn_rcpf(x); }

// ---------------------------------------------------------------------------
// Kernel 0: AGGD rho table (f64, matches numpy); alpha computed inline later.
// ---------------------------------------------------------------------------
__global__ __launch_bounds__(256) void tables_k(float* __restrict__ rgam) {
    int i = blockIdx.x * 256 + threadIdx.x;
    if (i >= NTAB) return;
    double g = 0.2 + (double)i * 0.001;
    rgam[i] = (float)exp(2.0 * lgamma(2.0 / g) - lgamma(1.0 / g) - lgamma(3.0 / g));
}

// ---------------------------------------------------------------------------
// MSCN on an LDS tile: CW word-cols, width TW words, NG row-groups of RPG
// rows (last group ORR-(NG-1)*RPG). Caller guards tid < CW*NG.
// ---------------------------------------------------------------------------
template <int CW, int TW, int NG, int RPG, int ORR>
__device__ __forceinline__ void mscn_tile(const uint* tin, uint* xs,
                                          const float* w1, int tid) {
    constexpr int TAIL = ORR - (NG - 1) * RPG;
    const int g = tid / CW, c = tid - g * CW;
    const int R0 = g * RPG;

    uint wA[4], wB[4];
    wA[0] = pack2(0.f, w1[0]);   wA[1] = pack2(w1[1], w1[2]);
    wA[2] = pack2(w1[3], w1[4]); wA[3] = pack2(w1[5], w1[6]);
    wB[0] = pack2(w1[0], w1[1]); wB[1] = pack2(w1[2], w1[3]);
    wB[2] = pack2(w1[4], w1[5]); wB[3] = pack2(w1[6], 0.f);

    auto horiz = [&](int row, f2v& o1, f2v& o2) {
        const uint* pw = &tin[row * TW + c];
        uint q0 = pw[0], q1 = pw[1], q2 = pw[2], q3 = pw[3], q4 = pw[4];
        uint p0 = pkmul(q0, q0), p1 = pkmul(q1, q1), p2 = pkmul(q2, q2),
             p3 = pkmul(q3, q3), p4 = pkmul(q4, q4);
        float s1A = fdot2f(q3, wA[3], fdot2f(q2, wA[2], fdot2f(q1, wA[1], fdot2f(q0, wA[0], 0.f))));
        float s2A = fdot2f(p3, wA[3], fdot2f(p2, wA[2], fdot2f(p1, wA[1], fdot2f(p0, wA[0], 0.f))));
        float s1B = fdot2f(q4, wB[3], fdot2f(q3, wB[2], fdot2f(q2, wB[1], fdot2f(q1, wB[0], 0.f))));
        float s2B = fdot2f(p4, wB[3], fdot2f(p3, wB[2], fdot2f(p2, wB[1], fdot2f(p1, wB[0], 0.f))));
        o1 = (f2v){s1A, s1B};
        o2 = (f2v){s2A, s2B};
    };

    f2v r1[7], r2[7];
#pragma unroll
    for (int ir = 0; ir < 6; ir++) horiz(R0 + ir, r1[ir], r2[ir]);

#define MSCN_STEP(u)                                                          \
    {                                                                         \
        horiz(R0 + (u) + 6, r1[((u) + 6) % 7], r2[((u) + 6) % 7]);            \
        f2v a1 = (f2v)(0.f), a2 = (f2v)(0.f);                                 \
        _Pragma("unroll")                                                     \
        for (int dy = 0; dy < 7; dy++) {                                      \
            a1 += r1[((u) + dy) % 7] * w1[dy];                                \
            a2 += r2[((u) + dy) % 7] * w1[dy];                                \
        }                                                                     \
        uint qc = tin[(R0 + (u) + 3) * TW + c + 2];                           \
        float v0a = flo(qc), v0b = fhi(qc);                                   \
        float xa = (v0a - a1.x) * rcpf(sqrtf(fabsf(a2.x - a1.x * a1.x)) + 1.f);\
        float xb = (v0b - a1.y) * rcpf(sqrtf(fabsf(a2.y - a1.y * a1.y)) + 1.f);\
        xs[(R0 + (u)) * CW + c] = pack2(xa, xb);                              \
    }

#pragma unroll
    for (int u = 0; u < TAIL; u++) MSCN_STEP(u)
    if constexpr (TAIL < RPG) {
        if (g < NG - 1) {
#pragma unroll
            for (int u = TAIL; u < RPG; u++) MSCN_STEP(u)
        }
    }
#undef MSCN_STEP
}

// ---------------------------------------------------------------------------
// AGGD feature core (quad version), NTHR-thread variant.
// ---------------------------------------------------------------------------
template <int BS, int NTHR>
__device__ __forceinline__ void feat_core(const uint* xs, float* red, float* tot,
                                          int b, int blk,
                                          const float* __restrict__ rgam,
                                          float* __restrict__ dfeat, int foff) {
    constexpr int WROW = BS / 2;
    constexpr int QUADS = BS * BS / 8;
    constexpr int QPR = WROW / 4;
    constexpr int NWAVE = NTHR / 64;
    const int tid = threadIdx.x;

    float ssq[5], sab[5], ssg[5];
    uint  cnt[5];
#pragma unroll
    for (int v = 0; v < 5; v++) { ssq[v] = sab[v] = ssg[v] = 0.f; cnt[v] = 0u; }

    const uint ONE2 = 0x3C003C00u;

    for (int k = 0; k < (QUADS + NTHR - 1) / NTHR; k++) {
        int idx = tid + k * NTHR;
        if (idx < QUADS) {
            int y  = idx / QPR;
            int q  = idx - y * QPR;
            int w0 = q * 4;
            int rb = y * WROW, rbm = (y ? y - 1 : BS - 1) * WROW;
            uint4 V = *(const uint4*)&xs[rb + w0];
            uint4 A = *(const uint4*)&xs[rbm + w0];
            uint WL = xs[rb  + (w0 ? w0 - 1 : WROW - 1)];
            uint AL = xs[rbm + (w0 ? w0 - 1 : WROW - 1)];
            uint AR = xs[rbm + ((w0 + 4 == WROW) ? 0 : w0 + 4)];
            uint Vw[4] = {V.x, V.y, V.z, V.w};
            uint Aw[4] = {A.x, A.y, A.z, A.w};
            uint vprev = WL, aprev = AL;
#pragma unroll
            for (int j = 0; j < 4; j++) {
                uint anext = (j < 3) ? Aw[j + 1] : AR;
                uint v0 = Vw[j];
                uint vv[5];
                vv[0] = v0;
                vv[1] = pkmul(v0, algn16(v0, vprev));
                vv[2] = pkmul(v0, Aw[j]);
                vv[3] = pkmul(v0, algn16(Aw[j], aprev));
                vv[4] = pkmul(v0, algn16(anext, Aw[j]));
#pragma unroll
                for (int v = 0; v < 5; v++) {
                    uint av = vv[v] & 0x7FFF7FFFu;
                    ssq[v] = fdot2f(vv[v], vv[v], ssq[v]);
                    sab[v] = fdot2f(av, ONE2, sab[v]);
                    ssg[v] = fdot2f(vv[v], av, ssg[v]);
                    cnt[v] += (vv[v] >> 15) & 0x00010001u;
                }
                vprev = v0; aprev = Aw[j];
            }
        }
    }

    const int wid = tid >> 6, lane = tid & 63;
#pragma unroll
    for (int v = 0; v < 5; v++) {
        float a = ssq[v], bb = sab[v], cc = ssg[v];
        float dd = (float)((cnt[v] & 0xFFFFu) + (cnt[v] >> 16));
        for (int off = 32; off >= 1; off >>= 1) {
            a += __shfl_down(a, off); bb += __shfl_down(bb, off);
            cc += __shfl_down(cc, off); dd += __shfl_down(dd, off);
        }
        if (lane == 0) {
            red[wid * 20 + v]      = a;
            red[wid * 20 + 5 + v]  = bb;
            red[wid * 20 + 10 + v] = cc;
            red[wid * 20 + 15 + v] = dd;
        }
    }
    __syncthreads();
    if (tid < 20) {
        float s = 0.f;
#pragma unroll
        for (int w = 0; w < NWAVE; w++) s += red[w * 20 + tid];
        tot[tid] = s;
    }
    __syncthreads();

    if (tid < 5) {
        const int v = tid;
        const float N = (float)(BS * BS);
        float ssqv = tot[v], sabv = tot[5 + v], ssgv = tot[10 + v], clv = tot[15 + v];
        float sql = fmaxf(0.5f * (ssqv - ssgv), 0.f);
        float sqr = fmaxf(0.5f * (ssqv + ssgv), 0.f);
        float cl = fmaxf(clv, 1.f), cr = fmaxf(N - clv, 1.f);
        float lstd = sqrtf(sql / cl), rstd = sqrtf(sqr / cr);
        float gh = lstd / fmaxf(rstd, 1e-12f);
        float mabs = sabv / N, msq = ssqv / N;
        float rhat = (mabs * mabs) / fmaxf(msq, 1e-12f);
        float gh2 = gh * gh;
        float target = rhat * (gh * gh2 + 1.f) * (gh + 1.f) / ((gh2 + 1.f) * (gh2 + 1.f));

        int lo = 0, hi = NTAB - 1, j = NTAB;
        while (lo <= hi) {
            int mid = (lo + hi) >> 1;
            if (rgam[mid] >= target) { j = mid; hi = mid - 1; } else lo = mid + 1;
        }
        int i0 = j > 0 ? j - 1 : 0;
        int i1 = j < NTAB ? j : NTAB - 1;
        float d0 = fabsf(rgam[i0] - target);
        float d1 = fabsf(rgam[i1] - target);
        int bi = (d1 < d0) ? i1 : i0;

        float alpha = (float)(0.2 + (double)bi * 0.001);
        float conv  = expf(0.5f * (lgammaf(1.f / alpha) - lgammaf(3.f / alpha)));
        float bl = lstd * conv, br = rstd * conv;
        float* outp = dfeat + ((size_t)b * 100 + blk) * 36 + foff;
        if (v == 0) {
            outp[0] = alpha;
            outp[1] = 0.5f * (bl + br);
        } else {
            float mean = (br - bl) * expf(lgammaf(2.f / alpha) - lgammaf(1.f / alpha));
            int base = 2 + (v - 1) * 4;
            outp[base + 0] = alpha; outp[base + 1] = mean;
            outp[base + 2] = bl;    outp[base + 3] = br;
        }
    }
}

// ---------------------------------------------------------------------------
// Kernel 1: fused scale-1, 512 threads (8 waves), two-phase staging.
// ---------------------------------------------------------------------------
__global__ __launch_bounds__(512, 8) void fused960_k(const float* __restrict__ X,
                                                     __half* __restrict__ img480,
                                                     const float* __restrict__ rgam,
                                                     float* __restrict__ dfeat,
                                                     WParams wp) {
    __shared__ __align__(16) uint tin[54 * 52];    // 11.2 KB (phase half-tile)
    __shared__ __align__(16) uint xs[96 * 48];     // 18.4 KB (full xn tile)
    __shared__ float red[160];
    __shared__ float tot[20];

    const int tid = threadIdx.x;
    const int b   = blockIdx.x / 100;
    const int blk = blockIdx.x % 100;
    const int br  = blk / 10, bc = blk % 10;
    const int by  = br * 96, bx = bc * 96;

    const float* img = X + (size_t)b * 960 * 960;
    const bool interior = (br >= 1) && (br <= 8) && (bc >= 1) && (bc <= 8);
    const float* wd = wp.wd;

#pragma unroll
    for (int ph = 0; ph < 2; ph++) {
        if (ph) __syncthreads();
        const int ry0 = by + ph * 48 - 3;
        if (interior) {
            const float4* base = reinterpret_cast<const float4*>(
                img + (size_t)ry0 * 960 + (bx - 4));
            for (int i = tid; i < 26 * 54; i += 512) {
                int r = i / 26, k2 = i - r * 26;
                float4 v = base[(size_t)r * 240 + k2];
                uint2 pr2; pr2.x = pack2(v.x, v.y); pr2.y = pack2(v.z, v.w);
                *(uint2*)&tin[r * 52 + 2 * k2] = pr2;
            }
        } else {
            for (int i = tid; i < 54 * 52; i += 512) {
                int r = i / 52, w = i - r * 52;
                int gy = ry0 + r; gy = gy < 0 ? 0 : (gy > 959 ? 959 : gy);
                int c0 = bx - 4 + 2 * w; int c0c = c0 < 0 ? 0 : (c0 > 959 ? 959 : c0);
                int c1 = c0 + 1;         int c1c = c1 < 0 ? 0 : (c1 > 959 ? 959 : c1);
                const float* rp = img + (size_t)gy * 960;
                tin[i] = pack2(rp[c0c], rp[c1c]);
            }
        }
        __syncthreads();

        // MSCN: 48 word-cols x 10 groups (9x5 + 1x3 rows) = 480 threads
        if (tid < 480) mscn_tile<48, 52, 10, 5, 48>(tin, xs + ph * 48 * 48, wp.w1, tid);

        // downsample rows j = ph*24 .. ph*24+23 (reads tin only)
#pragma unroll
        for (int k = 0; k < 3; k++) {
            int o = tid + k * 512;
            if (o < 1152) {
                int j = ph * 24 + o / 48, d = o - (o / 48) * 48;
                int Yd = by / 2 + j, Xd = bx / 2 + d;
                float mL = (bx + 2 * d - 1 >= 0) ? 1.f : 0.f;
                float acc = 0.f;
#pragma unroll
                for (int a = 0; a < 3; a++) {
                    int gy = 2 * Yd - 1 + a;
                    if (gy < 0) continue;         // zero pad (uniform)
                    int tr = gy - by - ph * 48 + 3;
                    uint u1 = tin[tr * 52 + d + 1];
                    uint u2 = tin[tr * 52 + d + 2];
                    acc += wd[a] * (wd[0] * fhi(u1) * mL + wd[1] * flo(u2) + wd[2] * fhi(u2));
                }
                img480[((size_t)b * 480 + Yd) * 480 + Xd] = __float2half(acc);
            }
        }
    }
    __syncthreads();

    feat_core<96, 512>(xs, red, tot, b, blk, rgam, dfeat, 0);
}

// ---------------------------------------------------------------------------
// Kernel 2: fused scale-2, 512 threads: 54x54 f16 tile, MSCN -> LDS, AGGD.
// ---------------------------------------------------------------------------
__global__ __launch_bounds__(512, 8) void fused480_k(const __half* __restrict__ img480,
                                                     const float* __restrict__ rgam,
                                                     float* __restrict__ dfeat,
                                                     WParams wp) {
    __shared__ __align__(16) uint tin[28 * 54];   // 6.0 KB
    __shared__ __align__(16) uint xs[24 * 48];    // 4.6 KB
    __shared__ float red[160];
    __shared__ float tot[20];

    const int tid = threadIdx.x;
    const int b   = blockIdx.x / 100;
    const int blk = blockIdx.x % 100;
    const int br  = blk / 10, bc = blk % 10;
    const int by  = br * 48, bx = bc * 48;

    const __half* img = img480 + (size_t)b * 480 * 480;
    const uint* gw = (const uint*)img;
    const bool interior = (br >= 1) && (br <= 8) && (bc >= 1) && (bc <= 8);

    if (interior) {
        for (int i = tid; i < 28 * 54; i += 512) {
            int r = i / 28, w = i - r * 28;
            tin[i] = gw[(((size_t)(by + r - 3) * 480 + (bx - 4)) >> 1) + w];
        }
    } else {
        for (int i = tid; i < 28 * 54; i += 512) {
            int r = i / 28, w = i - r * 28;
            int gy = by + r - 3; gy = gy < 0 ? 0 : (gy > 479 ? 479 : gy);
            int c0 = bx - 4 + 2 * w; int c0c = c0 < 0 ? 0 : (c0 > 479 ? 479 : c0);
            int c1 = c0 + 1;         int c1c = c1 < 0 ? 0 : (c1 > 479 ? 479 : c1);
            const __half* rp = img + (size_t)gy * 480;
            tin[i] = pack2(__half2float(rp[c0c]), __half2float(rp[c1c]));
        }
    }
    __syncthreads();

    // MSCN: 24 word-cols x 12 row-groups of 4 rows = 288 threads
    if (tid < 288) mscn_tile<24, 28, 12, 4, 48>(tin, xs, wp.w1, tid);
    __syncthreads();

    feat_core<48, 512>(xs, red, tot, b, blk, rgam, dfeat, 18);
}

// ---------------------------------------------------------------------------
// Kernel 3: per-batch stats + parallel SPD forward elimination.
// ---------------------------------------------------------------------------
__global__ __launch_bounds__(256) void final_k(const float* __restrict__ dfeat,
                                               const float* __restrict__ mu_pris,
                                               const float* __restrict__ cov_pris,
                                               float* __restrict__ out) {
    __shared__ float  ds[3600];
    __shared__ float  mu[36];
    __shared__ double M[36][37];
    __shared__ double rhs[36];
    __shared__ double qacc;
    const int b = blockIdx.x, tid = threadIdx.x;
    const float* src = dfeat + (size_t)b * 3600;
    for (int i = tid; i < 3600; i += 256) ds[i] = src[i];
    __syncthreads();
    if (tid < 36) {
        float s = 0.f;
        for (int n = 0; n < 100; n++) s += ds[n * 36 + tid];
        mu[tid] = s / 100.f;
    }
    __syncthreads();
    for (int i = tid; i < 3600; i += 256) ds[i] -= mu[i % 36];
    if (tid < 36) rhs[tid] = (double)mu_pris[tid] - (double)mu[tid];
    if (tid == 0) qacc = 0.0;
    __syncthreads();
    for (int e = tid; e < 1296; e += 256) {
        int f = e / 36, g = e % 36;
        float s = 0.f;
        for (int n = 0; n < 100; n++) s += ds[n * 36 + f] * ds[n * 36 + g];
        M[f][g] = 0.5 * ((double)cov_pris[e] + (double)(s / 99.f));
    }
    __syncthreads();
    for (int j = 0; j < 36; j++) {
        if (tid == 0) qacc += rhs[j] * rhs[j] / M[j][j];
        int i = j + 1 + tid;
        if (i < 36) {
            double L = M[i][j] / M[j][j];
            for (int k = j; k < 36; k++) M[i][k] -= L * M[j][k];
            rhs[i] -= L * rhs[j];
        }
        __syncthreads();
    }
    if (tid == 0) out[b] = sqrtf((float)(qacc > 0.0 ? qacc : 0.0));
}

// ---------------------------------------------------------------------------
static WParams make_weights() {
    WParams p;
    double wt[7], s = 0.0; const double sg = 7.0 / 6.0;
    for (int i = 0; i < 7; i++) { double d = i - 3; wt[i] = exp(-d * d / (2.0 * sg * sg)); s += wt[i]; }
    for (int i = 0; i < 7; i++) p.w1[i] = (float)(wt[i] / s);
    double e1 = exp(-2.0), sd = 1.0 + 2.0 * e1;
    p.wd[0] = p.wd[2] = (float)(e1 / sd);
    p.wd[1] = (float)(1.0 / sd);
    return p;
}

extern "C" void kernel_launch(void* const* d_in, const int* in_sizes, int n_in,
                              void* d_out, int out_size, void* d_ws, size_t ws_size,
                              hipStream_t stream) {
    const float* X        = (const float*)d_in[0];  // [32,1,960,960]
    const float* mu_pris  = (const float*)d_in[1];  // [36]
    const float* cov_pris = (const float*)d_in[2];  // [36,36]
    float* out = (float*)d_out;                     // [32]

    char* ws = (char*)d_ws;
    float*  rgam   = (float*)(ws);                      // 9801 f
    float*  dfeat  = (float*)(ws + 39424);              // 32*100*36 f
    __half* img480 = (__half*)(ws + 500224);            // 32*480*480 h

    WParams wp = make_weights();

    tables_k<<<(NTAB + 255) / 256, 256, 0, stream>>>(rgam);
    fused960_k<<<3200, 512, 0, stream>>>(X, img480, rgam, dfeat, wp);
    fused480_k<<<3200, 512, 0, stream>>>(img480, rgam, dfeat, wp);
    final_k<<<32, 256, 0, stream>>>(dfeat, mu_pris, cov_pris, out);
}

// Round 14
// 198.365 us; speedup vs baseline: 1.1634x; 1.1634x over previous
//
#include <hip/hip_runtime.h>
#include <hip/hip_fp16.h>
#include <math.h>

#define NTAB 9801
typedef unsigned int uint;
typedef float f2v __attribute__((ext_vector_type(2)));
typedef _Float16 h2v __attribute__((ext_vector_type(2)));

struct WParams { float w1[7]; float wd[3]; };

// ---------- packed-half helpers ----------
__device__ inline __half2 u2h2(uint u) { return __builtin_bit_cast(__half2, u); }
__device__ inline float flo(uint u) { return __low2float(u2h2(u)); }
__device__ inline float fhi(uint u) { return __high2float(u2h2(u)); }
__device__ inline uint pkmul(uint a, uint b) { return __builtin_bit_cast(uint, __hmul2(u2h2(a), u2h2(b))); }
__device__ inline uint pack2(float a, float b) {   // v_cvt_pkrtz_f16_f32
    return __builtin_bit_cast(uint, __builtin_amdgcn_cvt_pkrtz(a, b));
}
__device__ inline uint algn16(uint hi, uint lo) {   // (hi:lo)>>16 -> v_alignbit
    return (uint)((((unsigned long long)hi << 32) | lo) >> 16);
}
__device__ inline float fdot2f(uint a, uint b, float c) {
    return __builtin_amdgcn_fdot2(__builtin_bit_cast(h2v, a), __builtin_bit_cast(h2v, b), c, false);
}
__device__ inline float rcpf(float x) { return __builtin_amdgcn_rcpf(x); }

// ---------------------------------------------------------------------------
// Kernel 0: AGGD rho table (f64, matches numpy); alpha computed inline later.
// ---------------------------------------------------------------------------
__global__ __launch_bounds__(256) void tables_k(float* __restrict__ rgam) {
    int i = blockIdx.x * 256 + threadIdx.x;
    if (i >= NTAB) return;
    double g = 0.2 + (double)i * 0.001;
    rgam[i] = (float)exp(2.0 * lgamma(2.0 / g) - lgamma(1.0 / g) - lgamma(3.0 / g));
}

// ---------------------------------------------------------------------------
// MSCN on an LDS tile, register-pipelined: each step prefetches row u+7's
// 5 words before doing row u+6's horizontal math and the vertical conv for
// row u, so the LDS latency is covered by ~40 VALU insts. Center words kept
// in a 7-deep register ring (no per-step center read).
// CW word-cols, width TW words, NG row-groups of RPG rows (last group
// ORR-(NG-1)*RPG). Caller guards tid < CW*NG.
// ---------------------------------------------------------------------------
template <int CW, int TW, int NG, int RPG, int ORR>
__device__ __forceinline__ void mscn_tile(const uint* tin, uint* xs,
                                          const float* w1, int tid) {
    constexpr int TAIL = ORR - (NG - 1) * RPG;
    constexpr int LASTROW = ORR + 5;       // tile rows = ORR+6
    const int g = tid / CW, c = tid - g * CW;
    const int R0 = g * RPG;

    uint wA[4], wB[4];
    wA[0] = pack2(0.f, w1[0]);   wA[1] = pack2(w1[1], w1[2]);
    wA[2] = pack2(w1[3], w1[4]); wA[3] = pack2(w1[5], w1[6]);
    wB[0] = pack2(w1[0], w1[1]); wB[1] = pack2(w1[2], w1[3]);
    wB[2] = pack2(w1[4], w1[5]); wB[3] = pack2(w1[6], 0.f);

    auto mathq = [&](const uint* q, f2v& o1, f2v& o2) {
        uint p0 = pkmul(q[0], q[0]), p1 = pkmul(q[1], q[1]), p2 = pkmul(q[2], q[2]),
             p3 = pkmul(q[3], q[3]), p4 = pkmul(q[4], q[4]);
        float s1A = fdot2f(q[3], wA[3], fdot2f(q[2], wA[2], fdot2f(q[1], wA[1], fdot2f(q[0], wA[0], 0.f))));
        float s2A = fdot2f(p3, wA[3], fdot2f(p2, wA[2], fdot2f(p1, wA[1], fdot2f(p0, wA[0], 0.f))));
        float s1B = fdot2f(q[4], wB[3], fdot2f(q[3], wB[2], fdot2f(q[2], wB[1], fdot2f(q[1], wB[0], 0.f))));
        float s2B = fdot2f(p4, wB[3], fdot2f(p3, wB[2], fdot2f(p2, wB[1], fdot2f(p1, wB[0], 0.f))));
        o1 = (f2v){s1A, s1B};
        o2 = (f2v){s2A, s2B};
    };

    f2v r1[7], r2[7];
    uint cq[7];
    uint qcur0, qcur1, qcur2, qcur3, qcur4;

#pragma unroll
    for (int ir = 0; ir < 6; ir++) {
        const uint* pw = &tin[(R0 + ir) * TW + c];
        uint qq[5] = {pw[0], pw[1], pw[2], pw[3], pw[4]};
        mathq(qq, r1[ir], r2[ir]);
        cq[ir] = qq[2];
    }
    {
        const uint* pw = &tin[(R0 + 6) * TW + c];
        qcur0 = pw[0]; qcur1 = pw[1]; qcur2 = pw[2]; qcur3 = pw[3]; qcur4 = pw[4];
    }

#define MSCN_STEP(u)                                                          \
    {                                                                         \
        int nrow = R0 + (u) + 7; if (nrow > LASTROW) nrow = LASTROW;          \
        const uint* pw = &tin[nrow * TW + c];                                 \
        uint qn0 = pw[0], qn1 = pw[1], qn2 = pw[2], qn3 = pw[3], qn4 = pw[4]; \
        uint qq[5] = {qcur0, qcur1, qcur2, qcur3, qcur4};                     \
        mathq(qq, r1[((u) + 6) % 7], r2[((u) + 6) % 7]);                      \
        cq[((u) + 6) % 7] = qcur2;                                            \
        f2v a1 = (f2v)(0.f), a2 = (f2v)(0.f);                                 \
        _Pragma("unroll")                                                     \
        for (int dy = 0; dy < 7; dy++) {                                      \
            a1 += r1[((u) + dy) % 7] * w1[dy];                                \
            a2 += r2[((u) + dy) % 7] * w1[dy];                                \
        }                                                                     \
        uint qc = cq[((u) + 3) % 7];                                          \
        float v0a = flo(qc), v0b = fhi(qc);                                   \
        float xa = (v0a - a1.x) * rcpf(sqrtf(fabsf(a2.x - a1.x * a1.x)) + 1.f);\
        float xb = (v0b - a1.y) * rcpf(sqrtf(fabsf(a2.y - a1.y * a1.y)) + 1.f);\
        xs[(R0 + (u)) * CW + c] = pack2(xa, xb);                              \
        qcur0 = qn0; qcur1 = qn1; qcur2 = qn2; qcur3 = qn3; qcur4 = qn4;      \
    }

#pragma unroll
    for (int u = 0; u < TAIL; u++) MSCN_STEP(u)
    if constexpr (TAIL < RPG) {
        if (g < NG - 1) {
#pragma unroll
            for (int u = TAIL; u < RPG; u++) MSCN_STEP(u)
        }
    }
#undef MSCN_STEP
}

// ---------------------------------------------------------------------------
// AGGD feature core (quad version), register-pipelined: iteration k+1's five
// LDS loads are issued before iteration k's math.
// ---------------------------------------------------------------------------
template <int BS, int NTHR>
__device__ __forceinline__ void feat_core(const uint* xs, float* red, float* tot,
                                          int b, int blk,
                                          const float* __restrict__ rgam,
                                          float* __restrict__ dfeat, int foff) {
    constexpr int WROW = BS / 2;
    constexpr int QUADS = BS * BS / 8;     // NTHR <= QUADS holds for both scales
    constexpr int QPR = WROW / 4;
    constexpr int NWAVE = NTHR / 64;
    constexpr int KMAX = (QUADS + NTHR - 1) / NTHR;
    const int tid = threadIdx.x;

    float ssq[5], sab[5], ssg[5];
    uint  cnt[5];
#pragma unroll
    for (int v = 0; v < 5; v++) { ssq[v] = sab[v] = ssg[v] = 0.f; cnt[v] = 0u; }

    const uint ONE2 = 0x3C003C00u;

    uint4 Vc, Ac; uint WLc, ALc, ARc;
    {
        int idx = tid;     // k=0 always valid (NTHR <= QUADS)
        int y = idx / QPR, q = idx - y * QPR, w0 = q * 4;
        int rb = y * WROW, rbm = (y ? y - 1 : BS - 1) * WROW;
        Vc = *(const uint4*)&xs[rb + w0];
        Ac = *(const uint4*)&xs[rbm + w0];
        WLc = xs[rb  + (w0 ? w0 - 1 : WROW - 1)];
        ALc = xs[rbm + (w0 ? w0 - 1 : WROW - 1)];
        ARc = xs[rbm + ((w0 + 4 == WROW) ? 0 : w0 + 4)];
    }

#pragma unroll
    for (int k = 0; k < KMAX; k++) {
        uint4 Vn = Vc, An = Ac; uint WLn = WLc, ALn = ALc, ARn = ARc;
        int nidx = tid + (k + 1) * NTHR;
        if ((k + 1 < KMAX) && (nidx < QUADS)) {
            int y = nidx / QPR, q = nidx - y * QPR, w0 = q * 4;
            int rb = y * WROW, rbm = (y ? y - 1 : BS - 1) * WROW;
            Vn = *(const uint4*)&xs[rb + w0];
            An = *(const uint4*)&xs[rbm + w0];
            WLn = xs[rb  + (w0 ? w0 - 1 : WROW - 1)];
            ALn = xs[rbm + (w0 ? w0 - 1 : WROW - 1)];
            ARn = xs[rbm + ((w0 + 4 == WROW) ? 0 : w0 + 4)];
        }
        if (tid + k * NTHR < QUADS) {
            uint Vw[4] = {Vc.x, Vc.y, Vc.z, Vc.w};
            uint Aw[4] = {Ac.x, Ac.y, Ac.z, Ac.w};
            uint vprev = WLc, aprev = ALc;
#pragma unroll
            for (int j = 0; j < 4; j++) {
                uint anext = (j < 3) ? Aw[j + 1] : ARc;
                uint v0 = Vw[j];
                uint vv[5];
                vv[0] = v0;
                vv[1] = pkmul(v0, algn16(v0, vprev));
                vv[2] = pkmul(v0, Aw[j]);
                vv[3] = pkmul(v0, algn16(Aw[j], aprev));
                vv[4] = pkmul(v0, algn16(anext, Aw[j]));
#pragma unroll
                for (int v = 0; v < 5; v++) {
                    uint av = vv[v] & 0x7FFF7FFFu;
                    ssq[v] = fdot2f(vv[v], vv[v], ssq[v]);
                    sab[v] = fdot2f(av, ONE2, sab[v]);
                    ssg[v] = fdot2f(vv[v], av, ssg[v]);
                    cnt[v] += (vv[v] >> 15) & 0x00010001u;
                }
                vprev = v0; aprev = Aw[j];
            }
        }
        Vc = Vn; Ac = An; WLc = WLn; ALc = ALn; ARc = ARn;
    }

    const int wid = tid >> 6, lane = tid & 63;
#pragma unroll
    for (int v = 0; v < 5; v++) {
        float a = ssq[v], bb = sab[v], cc = ssg[v];
        float dd = (float)((cnt[v] & 0xFFFFu) + (cnt[v] >> 16));
        for (int off = 32; off >= 1; off >>= 1) {
            a += __shfl_down(a, off); bb += __shfl_down(bb, off);
            cc += __shfl_down(cc, off); dd += __shfl_down(dd, off);
        }
        if (lane == 0) {
            red[wid * 20 + v]      = a;
            red[wid * 20 + 5 + v]  = bb;
            red[wid * 20 + 10 + v] = cc;
            red[wid * 20 + 15 + v] = dd;
        }
    }
    __syncthreads();
    if (tid < 20) {
        float s = 0.f;
#pragma unroll
        for (int w = 0; w < NWAVE; w++) s += red[w * 20 + tid];
        tot[tid] = s;
    }
    __syncthreads();

    if (tid < 5) {
        const int v = tid;
        const float N = (float)(BS * BS);
        float ssqv = tot[v], sabv = tot[5 + v], ssgv = tot[10 + v], clv = tot[15 + v];
        float sql = fmaxf(0.5f * (ssqv - ssgv), 0.f);
        float sqr = fmaxf(0.5f * (ssqv + ssgv), 0.f);
        float cl = fmaxf(clv, 1.f), cr = fmaxf(N - clv, 1.f);
        float lstd = sqrtf(sql / cl), rstd = sqrtf(sqr / cr);
        float gh = lstd / fmaxf(rstd, 1e-12f);
        float mabs = sabv / N, msq = ssqv / N;
        float rhat = (mabs * mabs) / fmaxf(msq, 1e-12f);
        float gh2 = gh * gh;
        float target = rhat * (gh * gh2 + 1.f) * (gh + 1.f) / ((gh2 + 1.f) * (gh2 + 1.f));

        int lo = 0, hi = NTAB - 1, j = NTAB;
        while (lo <= hi) {
            int mid = (lo + hi) >> 1;
            if (rgam[mid] >= target) { j = mid; hi = mid - 1; } else lo = mid + 1;
        }
        int i0 = j > 0 ? j - 1 : 0;
        int i1 = j < NTAB ? j : NTAB - 1;
        float d0 = fabsf(rgam[i0] - target);
        float d1 = fabsf(rgam[i1] - target);
        int bi = (d1 < d0) ? i1 : i0;

        float alpha = (float)(0.2 + (double)bi * 0.001);
        float conv  = expf(0.5f * (lgammaf(1.f / alpha) - lgammaf(3.f / alpha)));
        float bl = lstd * conv, br = rstd * conv;
        float* outp = dfeat + ((size_t)b * 100 + blk) * 36 + foff;
        if (v == 0) {
            outp[0] = alpha;
            outp[1] = 0.5f * (bl + br);
        } else {
            float mean = (br - bl) * expf(lgammaf(2.f / alpha) - lgammaf(1.f / alpha));
            int base = 2 + (v - 1) * 4;
            outp[base + 0] = alpha; outp[base + 1] = mean;
            outp[base + 2] = bl;    outp[base + 3] = br;
        }
    }
}

// ---------------------------------------------------------------------------
// Kernel 1: fused scale-1, 256 threads, two-phase staging (R12 structure).
// ---------------------------------------------------------------------------
__global__ __launch_bounds__(256, 5) void fused960_k(const float* __restrict__ X,
                                                     __half* __restrict__ img480,
                                                     const float* __restrict__ rgam,
                                                     float* __restrict__ dfeat,
                                                     WParams wp) {
    __shared__ __align__(16) uint tin[54 * 52];    // 11.2 KB (phase half-tile)
    __shared__ __align__(16) uint xs[96 * 48];     // 18.4 KB (full xn tile)
    __shared__ float red[80];
    __shared__ float tot[20];

    const int tid = threadIdx.x;
    const int b   = blockIdx.x / 100;
    const int blk = blockIdx.x % 100;
    const int br  = blk / 10, bc = blk % 10;
    const int by  = br * 96, bx = bc * 96;

    const float* img = X + (size_t)b * 960 * 960;
    const bool interior = (br >= 1) && (br <= 8) && (bc >= 1) && (bc <= 8);
    const float* wd = wp.wd;

#pragma unroll
    for (int ph = 0; ph < 2; ph++) {
        if (ph) __syncthreads();
        const int ry0 = by + ph * 48 - 3;
        if (interior) {
            const float4* base = reinterpret_cast<const float4*>(
                img + (size_t)ry0 * 960 + (bx - 4));
            for (int i = tid; i < 26 * 54; i += 256) {
                int r = i / 26, k2 = i - r * 26;
                float4 v = base[(size_t)r * 240 + k2];
                uint2 pr2; pr2.x = pack2(v.x, v.y); pr2.y = pack2(v.z, v.w);
                *(uint2*)&tin[r * 52 + 2 * k2] = pr2;
            }
        } else {
            for (int i = tid; i < 54 * 52; i += 256) {
                int r = i / 52, w = i - r * 52;
                int gy = ry0 + r; gy = gy < 0 ? 0 : (gy > 959 ? 959 : gy);
                int c0 = bx - 4 + 2 * w; int c0c = c0 < 0 ? 0 : (c0 > 959 ? 959 : c0);
                int c1 = c0 + 1;         int c1c = c1 < 0 ? 0 : (c1 > 959 ? 959 : c1);
                const float* rp = img + (size_t)gy * 960;
                tin[i] = pack2(rp[c0c], rp[c1c]);
            }
        }
        __syncthreads();

        // MSCN: 48 word-cols x 5 groups (4x10 + 1x8 rows) = 240 threads
        if (tid < 240) mscn_tile<48, 52, 5, 10, 48>(tin, xs + ph * 48 * 48, wp.w1, tid);

        // downsample rows j = ph*24 .. ph*24+23 (reads tin only)
#pragma unroll
        for (int k = 0; k < 5; k++) {
            int o = tid + k * 256;
            if (o < 1152) {
                int j = ph * 24 + o / 48, d = o - (o / 48) * 48;
                int Yd = by / 2 + j, Xd = bx / 2 + d;
                float mL = (bx + 2 * d - 1 >= 0) ? 1.f : 0.f;
                float acc = 0.f;
#pragma unroll
                for (int a = 0; a < 3; a++) {
                    int gy = 2 * Yd - 1 + a;
                    if (gy < 0) continue;         // zero pad (uniform)
                    int tr = gy - by - ph * 48 + 3;
                    uint u1 = tin[tr * 52 + d + 1];
                    uint u2 = tin[tr * 52 + d + 2];
                    acc += wd[a] * (wd[0] * fhi(u1) * mL + wd[1] * flo(u2) + wd[2] * fhi(u2));
                }
                img480[((size_t)b * 480 + Yd) * 480 + Xd] = __float2half(acc);
            }
        }
    }
    __syncthreads();

    feat_core<96, 256>(xs, red, tot, b, blk, rgam, dfeat, 0);
}

// ---------------------------------------------------------------------------
// Kernel 2: fused scale-2: per 48x48 block, 54-row f16 tile, MSCN -> LDS,
// AGGD -> dfeat[18:36].
// ---------------------------------------------------------------------------
__global__ __launch_bounds__(256, 8) void fused480_k(const __half* __restrict__ img480,
                                                     const float* __restrict__ rgam,
                                                     float* __restrict__ dfeat,
                                                     WParams wp) {
    __shared__ __align__(16) uint tin[28 * 54];   // 6.0 KB
    __shared__ __align__(16) uint xs[24 * 48];    // 4.6 KB
    __shared__ float red[80];
    __shared__ float tot[20];

    const int tid = threadIdx.x;
    const int b   = blockIdx.x / 100;
    const int blk = blockIdx.x % 100;
    const int br  = blk / 10, bc = blk % 10;
    const int by  = br * 48, bx = bc * 48;

    const __half* img = img480 + (size_t)b * 480 * 480;
    const uint* gw = (const uint*)img;
    const bool interior = (br >= 1) && (br <= 8) && (bc >= 1) && (bc <= 8);

    if (interior) {
        for (int i = tid; i < 28 * 54; i += 256) {
            int r = i / 28, w = i - r * 28;
            tin[i] = gw[(((size_t)(by + r - 3) * 480 + (bx - 4)) >> 1) + w];
        }
    } else {
        for (int i = tid; i < 28 * 54; i += 256) {
            int r = i / 28, w = i - r * 28;
            int gy = by + r - 3; gy = gy < 0 ? 0 : (gy > 479 ? 479 : gy);
            int c0 = bx - 4 + 2 * w; int c0c = c0 < 0 ? 0 : (c0 > 479 ? 479 : c0);
            int c1 = c0 + 1;         int c1c = c1 < 0 ? 0 : (c1 > 479 ? 479 : c1);
            const __half* rp = img + (size_t)gy * 480;
            tin[i] = pack2(__half2float(rp[c0c]), __half2float(rp[c1c]));
        }
    }
    __syncthreads();

    // MSCN: 24 word-cols x 8 row-groups of 6 rows = 192 threads
    if (tid < 192) mscn_tile<24, 28, 8, 6, 48>(tin, xs, wp.w1, tid);
    __syncthreads();

    feat_core<48, 256>(xs, red, tot, b, blk, rgam, dfeat, 18);
}

// ---------------------------------------------------------------------------
// Kernel 3: per-batch stats + parallel SPD forward elimination.
// ---------------------------------------------------------------------------
__global__ __launch_bounds__(256) void final_k(const float* __restrict__ dfeat,
                                               const float* __restrict__ mu_pris,
                                               const float* __restrict__ cov_pris,
                                               float* __restrict__ out) {
    __shared__ float  ds[3600];
    __shared__ float  mu[36];
    __shared__ double M[36][37];
    __shared__ double rhs[36];
    __shared__ double qacc;
    const int b = blockIdx.x, tid = threadIdx.x;
    const float* src = dfeat + (size_t)b * 3600;
    for (int i = tid; i < 3600; i += 256) ds[i] = src[i];
    __syncthreads();
    if (tid < 36) {
        float s = 0.f;
        for (int n = 0; n < 100; n++) s += ds[n * 36 + tid];
        mu[tid] = s / 100.f;
    }
    __syncthreads();
    for (int i = tid; i < 3600; i += 256) ds[i] -= mu[i % 36];
    if (tid < 36) rhs[tid] = (double)mu_pris[tid] - (double)mu[tid];
    if (tid == 0) qacc = 0.0;
    __syncthreads();
    for (int e = tid; e < 1296; e += 256) {
        int f = e / 36, g = e % 36;
        float s = 0.f;
        for (int n = 0; n < 100; n++) s += ds[n * 36 + f] * ds[n * 36 + g];
        M[f][g] = 0.5 * ((double)cov_pris[e] + (double)(s / 99.f));
    }
    __syncthreads();
    for (int j = 0; j < 36; j++) {
        if (tid == 0) qacc += rhs[j] * rhs[j] / M[j][j];
        int i = j + 1 + tid;
        if (i < 36) {
            double L = M[i][j] / M[j][j];
            for (int k = j; k < 36; k++) M[i][k] -= L * M[j][k];
            rhs[i] -= L * rhs[j];
        }
        __syncthreads();
    }
    if (tid == 0) out[b] = sqrtf((float)(qacc > 0.0 ? qacc : 0.0));
}

// ---------------------------------------------------------------------------
static WParams make_weights() {
    WParams p;
    double wt[7], s = 0.0; const double sg = 7.0 / 6.0;
    for (int i = 0; i < 7; i++) { double d = i - 3; wt[i] = exp(-d * d / (2.0 * sg * sg)); s += wt[i]; }
    for (int i = 0; i < 7; i++) p.w1[i] = (float)(wt[i] / s);
    double e1 = exp(-2.0), sd = 1.0 + 2.0 * e1;
    p.wd[0] = p.wd[2] = (float)(e1 / sd);
    p.wd[1] = (float)(1.0 / sd);
    return p;
}

extern "C" void kernel_launch(void* const* d_in, const int* in_sizes, int n_in,
                              void* d_out, int out_size, void* d_ws, size_t ws_size,
                              hipStream_t stream) {
    const float* X        = (const float*)d_in[0];  // [32,1,960,960]
    const float* mu_pris  = (const float*)d_in[1];  // [36]
    const float* cov_pris = (const float*)d_in[2];  // [36,36]
    float* out = (float*)d_out;                     // [32]

    char* ws = (char*)d_ws;
    float*  rgam   = (float*)(ws);                      // 9801 f
    float*  dfeat  = (float*)(ws + 39424);              // 32*100*36 f
    __half* img480 = (__half*)(ws + 500224);            // 32*480*480 h

    WParams wp = make_weights();

    tables_k<<<(NTAB + 255) / 256, 256, 0, stream>>>(rgam);
    fused960_k<<<3200, 256, 0, stream>>>(X, img480, rgam, dfeat, wp);
    fused480_k<<<3200, 256, 0, stream>>>(img480, rgam, dfeat, wp);
    final_k<<<32, 256, 0, stream>>>(dfeat, mu_pris, cov_pris, out);
}